// Round 3
// baseline (14790.605 us; speedup 1.0000x reference)
//
#include <hip/hip_runtime.h>
#include <stdint.h>
#include <stddef.h>

// Persistent producer/consumer LSTM for T=1024, B=64, E=H=512 (fp32 in/out).
//
// Grid: 128 blocks x 512 threads. Block (gid,kid): batch group gid (16 b),
// j-slice kid (16 h-cols). Waves 0-3 = consumers (h recurrence), waves 4-7 =
// producers (x projection, runs ahead through an LDS ring, depth 8).
// Consumer wave w owns j-cols j0+w*4..+3, all 4 gates (16 z-cols), and the
// (b,j) cells for those cols: lane l -> (b=l>>2, jj=l&3), c in a register.
//
// h exchange across the 32 blocks of a group: each h element is ONE u32
// (t<<16)|bf16(h) stored agent-scope (bypasses non-coherent per-XCD L2s,
// lands in LLC). Readers poll the words themselves until all tags == t-1:
// no flags, no fences, no release drains. Double buffer by t&1 (stale tag
// in same parity is t-3; ws poison 0xAAAA never matches).
//
// Weights: bf16 hi+lo pairs in registers (128 VGPR/wave) => fp32-quality
// systematic accuracy; x also hi/lo split in the producer. h is single bf16
// (round-2 validated: absmax 3.9e-3 vs 1.625e-2 threshold).
//
// ws layout: hbuf u32[2][64][512] = 256 KB.

#define Tn 1024
#define Bn 64
#define Hn 512
#define RING 8

using bf16x8 = __attribute__((ext_vector_type(8))) __bf16;
using f32x4  = __attribute__((ext_vector_type(4))) float;
using u16x8  = __attribute__((ext_vector_type(8))) unsigned short;

__device__ __forceinline__ unsigned short f2bf(float f) {
    unsigned u = __builtin_bit_cast(unsigned, f);
    unsigned r = (u + 0x7FFFu + ((u >> 16) & 1u)) >> 16;
    return (unsigned short)r;
}
__device__ __forceinline__ float bf2f(unsigned short b) {
    unsigned u = ((unsigned)b) << 16;
    return __builtin_bit_cast(float, u);
}

__global__ __launch_bounds__(512, 2) void lstm_pc(
    const float* __restrict__ embeds,
    const float* __restrict__ wx0, const float* __restrict__ wh0, const float* __restrict__ bs0,
    const float* __restrict__ wx1, const float* __restrict__ wh1, const float* __restrict__ bs1,
    const float* __restrict__ wx2, const float* __restrict__ wh2, const float* __restrict__ bs2,
    const float* __restrict__ wx3, const float* __restrict__ wh3, const float* __restrict__ bs3,
    float* __restrict__ out, void* __restrict__ ws)
{
    __shared__ unsigned short htile[16][520];                 // h_{t-1} bf16, +8 pad
    __shared__ __align__(16) float ring[RING][4][64][4];      // zx slots [slot][wave][lane][4]
    __shared__ int ztag[RING][4];
    __shared__ int hdone[4];
    __shared__ int consdone[4];
    __shared__ float scr[4][16][20];                          // per-wave gate transpose

    const int tid  = threadIdx.x;
    const int wv   = tid >> 6;           // 0..7
    const int lane = tid & 63;
    const int q    = lane >> 4;
    const int n    = lane & 15;
    const bool producer = (wv >= 4);
    const int w    = wv & 3;             // producer p feeds consumer w=p

    const int gid = blockIdx.x >> 5;     // batch group (0..3)
    const int kid = blockIdx.x & 31;     // j-slice (0..31)
    const int b0  = gid * 16;
    const int j0  = kid * 16;

    uint32_t* hbuf = (uint32_t*)ws;      // [2][64][512] tagged words

    // ---- init LDS control state (only cross-wave tags need init) ----
    if (tid < RING * 4) ((int*)ztag)[tid] = 0;
    if (tid < 4) { hdone[tid] = 0; consdone[tid] = 0; }
    __syncthreads();                     // only block-wide barrier in the kernel

    // ---- publish h_0 = 0 with tag 0 (word == 0) ----
    if (!producer) {
        int bo = lane >> 2, jj = lane & 3;
        __hip_atomic_store(&hbuf[(size_t)(b0 + bo) * Hn + (j0 + w * 4 + jj)],
                           0u, __ATOMIC_RELAXED, __HIP_MEMORY_SCOPE_AGENT);
    }

    // ---- register weights: consumer = Wh, producer = Wx; bf16 hi/lo ----
    // z-col n = gate(n>>2)*4 + jj(n&3); matrix col = j0 + w*4 + jj.
    const int g    = n >> 2;
    const int colw = j0 + w * 4 + (n & 3);
    const float* Wp = producer
        ? (g == 0 ? wx0 : g == 1 ? wx1 : g == 2 ? wx2 : wx3)
        : (g == 0 ? wh0 : g == 1 ? wh1 : g == 2 ? wh2 : wh3);
    bf16x8 Whi[16], Wlo[16];
    for (int kk = 0; kk < 16; ++kk) {
        u16x8 hh, ll;
        #pragma unroll
        for (int i = 0; i < 8; ++i) {
            int k = kk * 32 + q * 8 + i;
            float wf = Wp[(size_t)k * Hn + colw];
            unsigned short hb = f2bf(wf);
            hh[i] = hb;
            ll[i] = f2bf(wf - bf2f(hb));
        }
        Whi[kk] = __builtin_bit_cast(bf16x8, hh);
        Wlo[kk] = __builtin_bit_cast(bf16x8, ll);
    }

    if (producer) {
        const float bias_l =
            (g == 0 ? bs0 : g == 1 ? bs1 : g == 2 ? bs2 : bs3)[colw];
        for (int t = 1; t <= Tn; ++t) {
            // ring credit: slot (t&7) free once consumer consumed step t-RING
            while (__hip_atomic_load(&consdone[w], __ATOMIC_ACQUIRE,
                                     __HIP_MEMORY_SCOPE_WORKGROUP) < t - RING) {}
            const float* xrow = embeds + ((size_t)(t - 1) * Bn + b0 + n) * Hn;
            f32x4 a0, a1, a2;
            a0[0] = bias_l; a0[1] = bias_l; a0[2] = bias_l; a0[3] = bias_l;
            a1[0] = a1[1] = a1[2] = a1[3] = 0.f;
            a2[0] = a2[1] = a2[2] = a2[3] = 0.f;
            #pragma unroll
            for (int kk = 0; kk < 16; ++kk) {
                float4 xA = *(const float4*)(xrow + kk * 32 + q * 8);
                float4 xB = *(const float4*)(xrow + kk * 32 + q * 8 + 4);
                float xs[8] = {xA.x, xA.y, xA.z, xA.w, xB.x, xB.y, xB.z, xB.w};
                u16x8 hh, ll;
                #pragma unroll
                for (int e = 0; e < 8; ++e) {
                    unsigned short hb = f2bf(xs[e]);
                    hh[e] = hb;
                    ll[e] = f2bf(xs[e] - bf2f(hb));
                }
                bf16x8 ah = __builtin_bit_cast(bf16x8, hh);
                bf16x8 al = __builtin_bit_cast(bf16x8, ll);
                a0 = __builtin_amdgcn_mfma_f32_16x16x32_bf16(ah, Whi[kk], a0, 0, 0, 0);
                a1 = __builtin_amdgcn_mfma_f32_16x16x32_bf16(ah, Wlo[kk], a1, 0, 0, 0);
                a2 = __builtin_amdgcn_mfma_f32_16x16x32_bf16(al, Whi[kk], a2, 0, 0, 0);
            }
            f32x4 zx;
            #pragma unroll
            for (int r = 0; r < 4; ++r) zx[r] = a0[r] + a1[r] + a2[r];
            int slot = t & (RING - 1);
            *(f32x4*)&ring[slot][w][lane][0] = zx;
            if (lane == 0)
                __hip_atomic_store(&ztag[slot][w], t, __ATOMIC_RELEASE,
                                   __HIP_MEMORY_SCOPE_WORKGROUP);
        }
    } else {
        const int bq = lane >> 2;                 // staging row (=owner b)
        const int k0 = w * 128 + (lane & 3) * 32; // staging k-slice start
        const int bo = lane >> 2, jj = lane & 3;  // owner cell
        float c_state = 0.f;

        for (int t = 1; t <= Tn; ++t) {
            // ---- 1. tagged-poll + load our k-slice of h_{t-1} ----
            const uint32_t* hrow =
                hbuf + ((size_t)(((t - 1) & 1) * Bn + b0 + bq)) * Hn + k0;
            const unsigned tg = (unsigned)(t - 1);
            unsigned long long v[16];
            #pragma unroll
            for (int i = 0; i < 16; ++i)
                v[i] = __hip_atomic_load((const unsigned long long*)hrow + i,
                                         __ATOMIC_RELAXED, __HIP_MEMORY_SCOPE_AGENT);
            unsigned pend = 0xFFFFu;
            while (pend) {
                unsigned np = 0;
                #pragma unroll
                for (int i = 0; i < 16; ++i) {
                    if (pend & (1u << i)) {
                        unsigned lo32 = (unsigned)v[i];
                        unsigned hi32 = (unsigned)(v[i] >> 32);
                        if (((lo32 >> 16) != tg) | ((hi32 >> 16) != tg)) {
                            v[i] = __hip_atomic_load(
                                (const unsigned long long*)hrow + i,
                                __ATOMIC_RELAXED, __HIP_MEMORY_SCOPE_AGENT);
                            np |= 1u << i;
                        }
                    }
                }
                pend = np;
            }
            // ---- 2. pack bf16 pairs -> htile ----
            uint32_t pk[16];
            #pragma unroll
            for (int i = 0; i < 16; ++i)
                pk[i] = __builtin_amdgcn_perm((unsigned)(v[i] >> 32),
                                              (unsigned)v[i], 0x05040100u);
            {
                uint4* dst = (uint4*)&htile[bq][k0];
                uint4 d;
                d.x = pk[0];  d.y = pk[1];  d.z = pk[2];  d.w = pk[3];  dst[0] = d;
                d.x = pk[4];  d.y = pk[5];  d.z = pk[6];  d.w = pk[7];  dst[1] = d;
                d.x = pk[8];  d.y = pk[9];  d.z = pk[10]; d.w = pk[11]; dst[2] = d;
                d.x = pk[12]; d.y = pk[13]; d.z = pk[14]; d.w = pk[15]; dst[3] = d;
            }
            if (lane == 0)
                __hip_atomic_store(&hdone[w], t, __ATOMIC_RELEASE,
                                   __HIP_MEMORY_SCOPE_WORKGROUP);
            // ---- 3. wait all 4 consumer waves staged their slice ----
            {
                int tv;
                do {
                    tv = __hip_atomic_load(&hdone[lane & 3], __ATOMIC_ACQUIRE,
                                           __HIP_MEMORY_SCOPE_WORKGROUP);
                } while (!__all(tv >= t));
            }
            // ---- 4. h MFMA (A = htile row n, B = Wh hi/lo) ----
            f32x4 aH, aL;
            aH[0] = aH[1] = aH[2] = aH[3] = 0.f;
            aL[0] = aL[1] = aL[2] = aL[3] = 0.f;
            #pragma unroll
            for (int kk = 0; kk < 16; ++kk) {
                bf16x8 ah = *(const bf16x8*)&htile[n][kk * 32 + q * 8];
                aH = __builtin_amdgcn_mfma_f32_16x16x32_bf16(ah, Whi[kk], aH, 0, 0, 0);
                aL = __builtin_amdgcn_mfma_f32_16x16x32_bf16(ah, Wlo[kk], aL, 0, 0, 0);
            }
            // ---- 5. fetch zx from ring ----
            while (__hip_atomic_load(&ztag[t & (RING - 1)][w], __ATOMIC_ACQUIRE,
                                     __HIP_MEMORY_SCOPE_WORKGROUP) < t) {}
            f32x4 zx = *(const f32x4*)&ring[t & (RING - 1)][w][lane][0];
            if (lane == 0)
                __hip_atomic_store(&consdone[w], t, __ATOMIC_RELEASE,
                                   __HIP_MEMORY_SCOPE_WORKGROUP);
            // ---- 6. activations (gate g uniform per lane) ----
            #pragma unroll
            for (int r = 0; r < 4; ++r) {
                float zv  = aH[r] + aL[r] + zx[r];
                float arg = (g == 0) ? -2.f * zv : -zv;
                float s   = __builtin_amdgcn_rcpf(1.f + __expf(arg));
                float act = (g == 0) ? (2.f * s - 1.f) : s;
                scr[w][q * 4 + r][n] = act;
            }
            // ---- 7. owner cell update (same wave: in-order LDS) ----
            {
                float gg = scr[w][bo][0 + jj];
                float ii = scr[w][bo][4 + jj];
                float ff = scr[w][bo][8 + jj];
                float oo = scr[w][bo][12 + jj];
                c_state = gg * ii + c_state * ff;
                float e2 = __expf(-2.f * c_state);
                float th = 2.f * __builtin_amdgcn_rcpf(1.f + e2) - 1.f;
                float hv = th * oo;
                out[((size_t)(t - 1) * Bn + b0 + bo) * Hn + (j0 + w * 4 + jj)] = hv;
                uint32_t word = ((uint32_t)t << 16) | (uint32_t)f2bf(hv);
                __hip_atomic_store(
                    &hbuf[(size_t)((t & 1) * Bn + b0 + bo) * Hn + (j0 + w * 4 + jj)],
                    word, __ATOMIC_RELAXED, __HIP_MEMORY_SCOPE_AGENT);
            }
        }
    }
}

extern "C" void kernel_launch(void* const* d_in, const int* in_sizes, int n_in,
                              void* d_out, int out_size, void* d_ws, size_t ws_size,
                              hipStream_t stream) {
    lstm_pc<<<dim3(128), dim3(512), 0, stream>>>(
        (const float*)d_in[0],
        (const float*)d_in[1], (const float*)d_in[2], (const float*)d_in[3],
        (const float*)d_in[4], (const float*)d_in[5], (const float*)d_in[6],
        (const float*)d_in[7], (const float*)d_in[8], (const float*)d_in[9],
        (const float*)d_in[10], (const float*)d_in[11], (const float*)d_in[12],
        (float*)d_out, d_ws);
}